// Round 13
// baseline (600.880 us; speedup 1.0000x reference)
//
#include <hip/hip_runtime.h>

#define D 128
#define BSH 8          // 256 nodes per bucket
#define CAP 10240      // slots per bucket (mean ~8192, sigma ~90 -> 22 sigma)
#define CH 8192        // edges per k_bin block (512 threads, 391 blocks)
                       // CH=4096 regressed (spans ~42B -> partial-line write amp 6x). [R10]

typedef unsigned short ushort_t;
typedef unsigned int uint_t;
typedef unsigned char uchar_t;

typedef __attribute__((ext_vector_type(8))) short frag_ab;   // 8 bf16 (4 VGPRs)
typedef __attribute__((ext_vector_type(4))) float frag_cd;   // 4 fp32 acc
typedef __attribute__((ext_vector_type(2))) float float2v;

union frag_u { ushort_t u[8]; frag_ab v; };

// Channel permutation: MFMA C-col c = j*16+l16 stored at position p = (c&15)*8 + (c>>4).
// Inverse: c = (p&7)*16 + (p>>3). Elementwise stages use positions; W2 rows and the
// finalize w3 contraction are permuted to match.
// fp8 gather table is QUARTER-MAJOR: quarter q holds positions [q*32, q*32+32) of all
// nodes as a 3.2MB slice (fits per-XCD 4MB L2). A lane's 8 epilogue channels
// (p = l16*8..+7) all fall inside quarter l16>>2 -> still one 8B store.

__device__ __forceinline__ float bf2f(ushort_t u) {
    union { uint_t i; float f; } v; v.i = ((uint_t)u) << 16; return v.f;
}
__device__ __forceinline__ ushort_t f2bf(float f) {
    union { float f; uint_t i; } v; v.f = f;
    uint_t u = v.i;
    u += 0x7fffu + ((u >> 16) & 1u);   // round-to-nearest-even
    return (ushort_t)(u >> 16);
}

// ---------------- edge binning into 256-node buckets, 4B packed entries ----------
// binA (dst-keyed): (src<<8) | (dst&255).  binB (src-keyed): (dst<<8) | (src&255).
// Direct scatter (proven R7-R12); counting-sort variant crashed in R11.
__launch_bounds__(512)
__global__ void k_bin(const int* __restrict__ src, const int* __restrict__ dst,
                      int* __restrict__ curA, int* __restrict__ curB,
                      uint_t* __restrict__ binA, uint_t* __restrict__ binB,
                      int E, int nb) {
    __shared__ int hA[512], hB[512], bA[512], bB[512];
    int tx = threadIdx.x;
    for (int i = tx; i < nb; i += 512) { hA[i] = 0; hB[i] = 0; }
    __syncthreads();

    int e0 = blockIdx.x * CH;
    int e1 = min(e0 + CH, E);

    for (int e = e0 + tx; e < e1; e += 512) {
        atomicAdd(&hA[dst[e] >> BSH], 1);
        atomicAdd(&hB[src[e] >> BSH], 1);
    }
    __syncthreads();
    for (int i = tx; i < nb; i += 512) {
        bA[i] = hA[i] ? atomicAdd(&curA[i], hA[i]) : 0;
        bB[i] = hB[i] ? atomicAdd(&curB[i], hB[i]) : 0;
        hA[i] = 0; hB[i] = 0;   // reuse as local cursors
    }
    __syncthreads();
    for (int e = e0 + tx; e < e1; e += 512) {
        int s = src[e], d = dst[e];
        int ka = d >> BSH, kb = s >> BSH;
        int pa = bA[ka] + atomicAdd(&hA[ka], 1);
        int pb = bB[kb] + atomicAdd(&hB[kb], 1);
        if (pa < CAP) binA[(size_t)ka * CAP + pa] = ((uint_t)s << 8) | (uint_t)(d & 255);
        if (pb < CAP) binB[(size_t)kb * CAP + pb] = ((uint_t)d << 8) | (uint_t)(s & 255);
    }
}

// ---------------- per-bucket: degree + dinv + row ranges + CSR fill ----------------
__launch_bounds__(1024)
__global__ void k_csr(const uint_t* __restrict__ binA, const int* __restrict__ curA,
                      float* __restrict__ dinv, int* __restrict__ row_beg,
                      int* __restrict__ row_end, int* __restrict__ csr_src, int N) {
    __shared__ int hist[256];
    __shared__ int scan[256];
    int b = blockIdx.x;
    int tx = threadIdx.x;
    int cnt = min(curA[b], CAP);
    const uint_t* eb = binA + (size_t)b * CAP;

    if (tx < 256) hist[tx] = 0;
    __syncthreads();
    for (int e = tx; e < cnt; e += 1024)
        atomicAdd(&hist[eb[e] & 255u], 1);
    __syncthreads();
    int v = 0;
    if (tx < 256) { v = hist[tx]; scan[tx] = v; }
    __syncthreads();
    for (int dd = 1; dd < 256; dd <<= 1) {
        int t = 0;
        if (tx < 256 && tx >= dd) t = scan[tx - dd];
        __syncthreads();
        if (tx < 256) scan[tx] += t;
        __syncthreads();
    }
    if (tx < 256) {
        int my_excl = scan[tx] - v;
        int node = b * 256 + tx;
        if (node < N) {
            dinv[node] = rsqrtf((float)(v + 1));        // +1 self-loop
            row_beg[node] = b * CAP + my_excl;
            row_end[node] = b * CAP + my_excl + v;
        }
        hist[tx] = my_excl;                              // reuse as fill cursor
    }
    __syncthreads();
    for (int e = tx; e < cnt; e += 1024) {
        uint_t pk = eb[e];
        int pos = b * CAP + atomicAdd(&hist[pk & 255u], 1);
        csr_src[pos] = (int)(pk >> 8);
    }
}

// ---------------- weight pack + bias permute (one launch) ----------------
__global__ void k_wpack(const float* __restrict__ W1, const float* __restrict__ W2,
                        ushort_t* __restrict__ h1, ushort_t* __restrict__ l1,
                        ushort_t* __restrict__ h2, ushort_t* __restrict__ l2,
                        const float* __restrict__ b1, const float* __restrict__ b2,
                        float* __restrict__ bp1, float* __restrict__ bp2) {
    if (blockIdx.x == 128) {
        int p = threadIdx.x;
        if (p < 128) {
            int c = (p & 7) * 16 + (p >> 3);
            bp1[p] = b1[c];
            bp2[p] = b2[c];
        }
        return;
    }
    int gid = blockIdx.x * 256 + threadIdx.x;      // 0..32767
    int which = gid >> 14;
    int idx = gid & 16383;
    int k = idx >> 7, n = idx & 127;
    float w = which ? W2[(((k & 7) * 16) + (k >> 3)) * 128 + n] : W1[idx];
    ushort_t h = f2bf(w);
    ushort_t l = f2bf(w - bf2f(h));                // residual, makes W effectively fp32
    int c = k >> 5, quad = (k >> 3) & 3, jj = k & 7;
    int j = n >> 4, l16 = n & 15;
    int lane = quad * 16 + l16;
    int dest = ((c * 8 + j) * 64 + lane) * 8 + jj;
    if (which) { h2[dest] = h; l2[dest] = l; }
    else       { h1[dest] = h; l1[dest] = l; }
}

// ---------------- MFMA GEMM, fused scale+fp8 epilogue (quarter-major table) -------
// C8q[q][row][32ch] = fp8_e4m3( dinv[row] * GEMM[c_orig(p)] ), q = p>>5.
template <int IN_F32>
__launch_bounds__(256)
__global__ void gemm_mfma(const void* __restrict__ Av, const ushort_t* __restrict__ Whi,
                          const ushort_t* __restrict__ Wlo, const float* __restrict__ dinv,
                          uint_t* __restrict__ C32, int nrows, int qs /* = N*8 dwords */) {
    int wave = threadIdx.x >> 6;
    int lane = threadIdx.x & 63;
    int quad = lane >> 4, l16 = lane & 15;
    int base = blockIdx.x * 128 + wave * 32;

    frag_cd acc[2][8];
#pragma unroll
    for (int rt = 0; rt < 2; rt++)
#pragma unroll
        for (int j = 0; j < 8; j++) acc[rt][j] = (frag_cd)0.f;

    const ushort_t* Ab = (const ushort_t*)Av;
    const float* Af = (const float*)Av;

#pragma unroll
    for (int c = 0; c < 4; c++) {
        frag_ab afrag[2];
        int koff = c * 32 + quad * 8;
#pragma unroll
        for (int rt = 0; rt < 2; rt++) {
            int row = min(base + rt * 16 + l16, nrows - 1);
            if (IN_F32) {
                const float* ap = Af + (size_t)row * D + koff;
                float4 a0 = *(const float4*)ap;
                float4 a1 = *(const float4*)(ap + 4);
                frag_u fu;
                fu.u[0] = f2bf(a0.x); fu.u[1] = f2bf(a0.y);
                fu.u[2] = f2bf(a0.z); fu.u[3] = f2bf(a0.w);
                fu.u[4] = f2bf(a1.x); fu.u[5] = f2bf(a1.y);
                fu.u[6] = f2bf(a1.z); fu.u[7] = f2bf(a1.w);
                afrag[rt] = fu.v;
            } else {
                afrag[rt] = *(const frag_ab*)(Ab + (size_t)row * D + koff);
            }
        }
#pragma unroll
        for (int j = 0; j < 8; j++) {
            frag_ab bh = *(const frag_ab*)(Whi + (((c * 8 + j) * 64 + lane) * 8));
            frag_ab bl = *(const frag_ab*)(Wlo + (((c * 8 + j) * 64 + lane) * 8));
#pragma unroll
            for (int rt = 0; rt < 2; rt++) {
                acc[rt][j] = __builtin_amdgcn_mfma_f32_16x16x32_bf16(afrag[rt], bh,
                                                                     acc[rt][j], 0, 0, 0);
                acc[rt][j] = __builtin_amdgcn_mfma_f32_16x16x32_bf16(afrag[rt], bl,
                                                                     acc[rt][j], 0, 0, 0);
            }
        }
    }

    uint_t* qbase = C32 + (size_t)(l16 >> 2) * (size_t)qs + (l16 & 3) * 2;
#pragma unroll
    for (int rt = 0; rt < 2; rt++) {
        int rbase = base + rt * 16 + quad * 4;
#pragma unroll
        for (int reg = 0; reg < 4; reg++) {
            int row = rbase + reg;
            if (row < nrows) {
                float dv = dinv[row];
                uint_t d0 = (uint_t)__builtin_amdgcn_cvt_pk_fp8_f32(
                    acc[rt][0][reg] * dv, acc[rt][1][reg] * dv, 0, false);
                d0 = (uint_t)__builtin_amdgcn_cvt_pk_fp8_f32(
                    acc[rt][2][reg] * dv, acc[rt][3][reg] * dv, (int)d0, true);
                uint_t d1 = (uint_t)__builtin_amdgcn_cvt_pk_fp8_f32(
                    acc[rt][4][reg] * dv, acc[rt][5][reg] * dv, 0, false);
                d1 = (uint_t)__builtin_amdgcn_cvt_pk_fp8_f32(
                    acc[rt][6][reg] * dv, acc[rt][7][reg] * dv, (int)d1, true);
                uint2 o; o.x = d0; o.y = d1;
                *(uint2*)(qbase + (size_t)row * 8) = o;
            }
        }
    }
}

// ---------------- aggregation, quarter-pass (L2-resident 3.2MB slice) -------------
// Pass q: out[n][q*32..+32) = relu?( dn*( uq[n] + sum_e uq[src] ) + bias )
// One wave per (node, quarter). 8 lanes per edge (32B row), 8 edge-groups/wave,
// 16 edges in flight. Butterfly over group bits merges partials. All csr_src
// reads min-clamped in-bounds; masked gathers zeroed (fp8 0x00 = 0.0).
__launch_bounds__(256)
__global__ void agg8(const uint_t* __restrict__ t8, const int* __restrict__ csr_src,
                     const int* __restrict__ row_beg, const int* __restrict__ row_end,
                     const float* __restrict__ dinv, const float* __restrict__ bias,
                     uint_t* __restrict__ out, int n, int do_relu, int bpq, int qs) {
    int q = blockIdx.x / bpq;               // blocks dispatch ~in order: quarters
    int node = (blockIdx.x - q * bpq) * 4 + (threadIdx.x >> 6);   // temporally separated
    if (node >= n) return;
    int lane = threadIdx.x & 63;
    int g = lane >> 3;                      // edge group 0..7
    uint_t cl = (uint_t)(lane & 7);         // dword within 32B quarter-row

    const uint_t* tq = t8 + (size_t)q * (size_t)qs;

    int beg = row_beg[node];
    int end = row_end[node];
    float dn = dinv[node];

    float2v accA = {0.f, 0.f}, accB = {0.f, 0.f};

    for (int eb = beg; eb < end; eb += 16) {
        int e0 = eb + g;
        int e1 = eb + 8 + g;
        int i0 = min(e0, end - 1);          // always in-bounds (end > beg here)
        int i1 = min(e1, end - 1);
        uint_t s0 = (uint_t)csr_src[i0];
        uint_t s1 = (uint_t)csr_src[i1];
        uint_t w0 = tq[s0 * 8u + cl];
        uint_t w1 = tq[s1 * 8u + cl];
        w0 = (e0 < end) ? w0 : 0u;
        w1 = (e1 < end) ? w1 : 0u;
        accA += __builtin_amdgcn_cvt_pk_f32_fp8(w0, false);
        accB += __builtin_amdgcn_cvt_pk_f32_fp8(w0, true);
        accA += __builtin_amdgcn_cvt_pk_f32_fp8(w1, false);
        accB += __builtin_amdgcn_cvt_pk_f32_fp8(w1, true);
    }

    // merge the 8 edge-group partials (lane bits 3..5)
    float a0 = accA.x, a1 = accA.y, a2 = accB.x, a3 = accB.y;
#pragma unroll
    for (int m = 8; m <= 32; m <<= 1) {
        a0 += __shfl(a0, lane ^ m, 64);
        a1 += __shfl(a1, lane ^ m, 64);
        a2 += __shfl(a2, lane ^ m, 64);
        a3 += __shfl(a3, lane ^ m, 64);
    }

    if (g == 0) {
        uint_t ws = tq[(uint_t)node * 8u + cl];     // self term (pre-scaled)
        float2v slo = __builtin_amdgcn_cvt_pk_f32_fp8(ws, false);
        float2v shi = __builtin_amdgcn_cvt_pk_f32_fp8(ws, true);
        float4 bb = ((const float4*)bias)[q * 8 + (int)cl];
        float o0 = dn * (a0 + slo.x) + bb.x;
        float o1 = dn * (a1 + slo.y) + bb.y;
        float o2 = dn * (a2 + shi.x) + bb.z;
        float o3 = dn * (a3 + shi.y) + bb.w;
        if (do_relu) {
            o0 = fmaxf(o0, 0.f); o1 = fmaxf(o1, 0.f);
            o2 = fmaxf(o2, 0.f); o3 = fmaxf(o3, 0.f);
        }
        uint2 ow;
        ow.x = (uint_t)f2bf(o0) | ((uint_t)f2bf(o1) << 16);
        ow.y = (uint_t)f2bf(o2) | ((uint_t)f2bf(o3) << 16);
        *(uint2*)(out + (size_t)node * 64 + q * 16 + cl * 2) = ow;
    }
}

// ---------------- fused ow + weighted reduce (one block per 256-node bucket) -------
__launch_bounds__(512)
__global__ void wreduce(const ushort_t* __restrict__ h, const uint_t* __restrict__ binB,
                        const int* __restrict__ curB, const float* __restrict__ dinv,
                        float* __restrict__ v, int n) {
    __shared__ float owacc[256];
    __shared__ float s[512];
    int b = blockIdx.x;
    int tx = threadIdx.x;
    if (tx < 256) owacc[tx] = 0.f;
    __syncthreads();
    int cnt = min(curB[b], CAP);
    const uint_t* eb = binB + (size_t)b * CAP;
    for (int e = tx; e < cnt; e += 512) {
        uint_t pk = eb[e];
        atomicAdd(&owacc[pk & 255u], dinv[pk >> 8]);
    }
    __syncthreads();

    int c = tx & 127;
    int rg = tx >> 7;                    // 0..3
    int base = b * 256;
    int lim = min(base + 256, n);
    float acc = 0.f;
    for (int r = base + rg; r < lim; r += 4) {
        float dv = dinv[r];
        float cv = dv * (dv + owacc[r - base]);
        acc += cv * bf2f(h[(size_t)r * D + c]);
    }
    s[tx] = acc;
    __syncthreads();
    if (tx < 128)
        atomicAdd(&v[c], (s[tx] + s[tx + 128]) + (s[tx + 256] + s[tx + 384]));
}

// ---------------- finalize: out[j] = (v @ w3)[j]/N + b3[j], v is permuted ----------
__global__ void finalize(const float* __restrict__ v, const float* __restrict__ w3,
                         const float* __restrict__ b3, float* __restrict__ out, float invn) {
    __shared__ float sv[D];
    int j = threadIdx.x;
    sv[j] = v[j];
    __syncthreads();
    float acc = 0.f;
    for (int k = 0; k < D; k++) {
        int p = (k & 15) * 8 + (k >> 4);    // position of original channel k
        acc += sv[p] * w3[(size_t)k * D + j];
    }
    out[j] = acc * invn + b3[j];
}

extern "C" void kernel_launch(void* const* d_in, const int* in_sizes, int n_in,
                              void* d_out, int out_size, void* d_ws, size_t ws_size,
                              hipStream_t stream) {
    const float* x   = (const float*)d_in[0];
    const int*   ei  = (const int*)d_in[1];
    const float* w1  = (const float*)d_in[2];
    const float* b1  = (const float*)d_in[3];
    const float* w2  = (const float*)d_in[4];
    const float* b2  = (const float*)d_in[5];
    const float* w3  = (const float*)d_in[6];
    const float* b3  = (const float*)d_in[7];
    float* out = (float*)d_out;

    const int N = in_sizes[0] / D;       // 100000
    const int E = in_sizes[1] / 2;       // 3200000
    const int* src = ei;
    const int* dst = ei + E;
    const int nb = (N + 255) >> 8;       // 391 buckets of 256 nodes

    // ---- workspace layout ----
    char* p = (char*)d_ws;
    auto alloc = [&](size_t bytes) -> char* {
        char* r = p;
        p += (bytes + 255) & ~(size_t)255;
        return r;
    };
    char*     zbeg     = p;
    int*      curA     = (int*)alloc(512 * 4);
    int*      curB     = (int*)alloc(512 * 4);
    float*    v        = (float*)alloc((size_t)D * 4);
    char*     zend     = p;
    float*    dinv     = (float*)alloc((size_t)N * 4);
    int*      row_beg  = (int*)alloc((size_t)N * 4);
    int*      row_end  = (int*)alloc((size_t)N * 4);
    ushort_t* wp1h     = (ushort_t*)alloc(16384 * 2);
    ushort_t* wp1l     = (ushort_t*)alloc(16384 * 2);
    ushort_t* wp2h     = (ushort_t*)alloc(16384 * 2);
    ushort_t* wp2l     = (ushort_t*)alloc(16384 * 2);
    float*    bp1      = (float*)alloc(D * 4);
    float*    bp2      = (float*)alloc(D * 4);
    uint_t*   binA     = (uint_t*)alloc((size_t)nb * CAP * 4);  // 16 MB
    uint_t*   binB     = (uint_t*)alloc((size_t)nb * CAP * 4);  // 16 MB
    int*      csr_src  = (int*)alloc((size_t)nb * CAP * 4);     // 16 MB
    ushort_t* bufH     = (ushort_t*)alloc((size_t)N * D * 2);   // bf16 agg out
    uint_t*   buf8     = (uint_t*)alloc((size_t)N * 32 * 4);    // fp8 table, 4 quarters
    (void)ws_size;

    const int gG  = (N + 127) / 128;     // MFMA gemm grid
    const int bpq = (N + 3) / 4;         // agg blocks per quarter
    const int qs  = N * 8;               // quarter stride in dwords

    // zero curA/curB/v
    hipMemsetAsync(zbeg, 0, (size_t)(zend - zbeg), stream);

    // weight packing + bias permute (single launch, independent of graph work)
    k_wpack<<<129, 256, 0, stream>>>(w1, w2, wp1h, wp1l, wp2h, wp2l, b1, b2, bp1, bp2);

    // graph preprocessing: bin edges (4B entries), then per-bucket degree/CSR
    k_bin<<<(E + CH - 1) / CH, 512, 0, stream>>>(src, dst, curA, curB, binA, binB, E, nb);
    k_csr<<<nb, 1024, 0, stream>>>(binA, curA, dinv, row_beg, row_end, csr_src, N);

    // layer 1: u1 = fp8(dinv * (x@w1)) quarter-major ; h1 = relu(dn*(sum u1)+b1)
    gemm_mfma<1><<<gG, 256, 0, stream>>>(x, wp1h, wp1l, dinv, buf8, N, qs);
    agg8<<<4 * bpq, 256, 0, stream>>>(buf8, csr_src, row_beg, row_end, dinv, bp1,
                                      (uint_t*)bufH, N, 1, bpq, qs);
    // layer 2 (A permuted, W2 rows permuted to match)
    gemm_mfma<0><<<gG, 256, 0, stream>>>(bufH, wp2h, wp2l, dinv, buf8, N, qs);
    agg8<<<4 * bpq, 256, 0, stream>>>(buf8, csr_src, row_beg, row_end, dinv, bp2,
                                      (uint_t*)bufH, N, 1, bpq, qs);
    // layer 3 collapsed: v = sum_i cvec[i]*h2[i] (ow fused in) ; out = v@w3/N + b3
    wreduce<<<nb, 512, 0, stream>>>(bufH, binB, curB, dinv, v, N);
    finalize<<<1, D, 0, stream>>>(v, w3, b3, out, 1.0f / (float)N);
}